// Round 9
// baseline (452.692 us; speedup 1.0000x reference)
//
#include <hip/hip_runtime.h>
#include <hip/hip_fp16.h>

// Fixed problem shape
#define TOK   64
#define INF   4096
#define OUTF  11008
#define NUMEL (OUTF * INF)        // 45088768
#define NSLC  (NUMEL / 64)        // 704512 64-element slices
#define NSEED (NSLC / 64)         // 11008 seed intervals (4096 positions each)
#define NBLK  (OUTF / 16)         // 688 N-tiles
#define KSPL  4                   // K-split -> 2752 blocks, K=1024 each
#define OUTN  (TOK * OUTF)        // 704512 output elems

// Harness dtypes: fp16 arrays arrive as fp32; ints as int32; output fp32.
typedef __attribute__((ext_vector_type(8))) _Float16 half8;
typedef __attribute__((ext_vector_type(4))) _Float16 half4;
typedef __attribute__((ext_vector_type(4))) float floatx4;
typedef __attribute__((ext_vector_type(4), aligned(4))) int int4u;   // dword-aligned dwordx4
typedef __attribute__((ext_vector_type(4))) int int4a;               // 16B-aligned dwordx4

// ---------------------------------------------------------------------------
// Seed kernel: seed[j] = lower_bound(fp16_pos, j*4096), j = 0..NSEED.
// 11K independent full binary searches (~17 iters) — a few us.
// ---------------------------------------------------------------------------
__global__ __launch_bounds__(256) void seed_kernel(
    const int* __restrict__ fppos, int nf, int* __restrict__ seed) {
  const int j = blockIdx.x * 256 + threadIdx.x;
  if (j <= NSEED) {
    const int target = j * 4096;
    int lo = 0, hi = nf;
    while (lo < hi) {
      const int mid = (lo + hi) >> 1;
      if (fppos[mid] < target) lo = mid + 1; else hi = mid;
    }
    seed[j] = lo;
  }
}

// ---------------------------------------------------------------------------
// Precompute: (a) x fp32 -> fp16 (512 KB, L2-resident GEMM A),
// (b) per-64-slice meta[s] = {c0 = lower_bound(fp16_pos, 64*s),
//     outlier mask lo, mask hi, pad} — one 16 B record.
// R9: search bounded by seed interval (mean ~11 entries -> ~4 dependent
// loads instead of ~19).
// ---------------------------------------------------------------------------
__global__ __launch_bounds__(256) void precompute_kernel(
    const float* __restrict__ x, const int* __restrict__ fppos, int nf,
    const int* __restrict__ seed, _Float16* __restrict__ x16,
    int* __restrict__ meta) {
  const int t = blockIdx.x * 256 + threadIdx.x;
  if (t < (TOK * INF) / 4) {
    const floatx4 f = *(const floatx4*)&x[t * 4];
    half4 h;
    h[0] = (_Float16)f[0]; h[1] = (_Float16)f[1];
    h[2] = (_Float16)f[2]; h[3] = (_Float16)f[3];
    *(half4*)&x16[t * 4] = h;
  }
  if (t < NSLC) {
    const int target = t << 6;
    int lo = seed[t >> 6], hi = seed[(t >> 6) + 1];
    while (lo < hi) {
      const int mid = (lo + hi) >> 1;
      if (fppos[mid] < target) lo = mid + 1; else hi = mid;
    }
    unsigned long long mask = 0ull;
    int j = lo;
    while (j < nf) {                 // mean 0.17 iters; P(>2) ~ 1e-4
      const int d = fppos[j] - target;
      if (d >= 64) break;
      mask |= 1ull << d;
      ++j;
    }
    int4a mv;
    mv[0] = lo;
    mv[1] = (int)(unsigned)(mask & 0xffffffffu);
    mv[2] = (int)(unsigned)(mask >> 32);
    mv[3] = 0;
    *(int4a*)&meta[t * 4] = mv;
  }
}

// ---------------------------------------------------------------------------
// meta_window1 (R3-R8 verified verbatim): compacted i8 index i0 of position
// p0 + 8-bit outlier window. off multiple of 8 -> never straddles halves.
// ---------------------------------------------------------------------------
__device__ __forceinline__ void meta_window1(const int p0, const int4a mv,
                                             int& i0, unsigned& m8) {
  const unsigned mlo = (unsigned)mv[1];
  const unsigned mhi = (unsigned)mv[2];
  const int off = p0 & 63;
  m8 = 0xffu & (off < 32 ? (mlo >> off) : (mhi >> (off - 32)));
  const unsigned bl = (off >= 32) ? mlo : (mlo & ((1u << off) - 1u));
  const unsigned bh = (off >= 32) ? (mhi & ((1u << (off - 32)) - 1u)) : 0u;
  i0 = p0 - mv[0] - (__popc(bl) + __popc(bh));
}

// ---------------------------------------------------------------------------
// finish_slot (R2-R8 verbatim): SLOW path only (>2 outliers in one 8-slot,
// ~1e-6 of slots; wave-uniformly skipped otherwise). Inline fpdat loads ok.
// ---------------------------------------------------------------------------
__device__ __forceinline__ half8 finish_slot(
    const unsigned m8, const int i0, const int p0, const float s,
    const int (&l)[8], const int* __restrict__ i8,
    const float* __restrict__ fpdat, const int n8) {
  const int f = (int)m8;
  float ov[8];
#pragma unroll
  for (int e = 0; e < 8; ++e) ov[e] = 0.f;
  if (f) {
    int fi = p0 - i0;  // c0 + (#outliers below p0)
#pragma unroll
    for (int e = 0; e < 8; ++e) {
      if ((f >> e) & 1) { ov[e] = fpdat[fi]; ++fi; }
    }
  }

  half8 oh;
  if (i0 + 8 <= n8) {
    if (f == 0) {
#pragma unroll
      for (int e = 0; e < 8; ++e) oh[e] = (_Float16)((float)l[e] * s);
    } else {
      int q = 0;
#pragma unroll
      for (int e = 0; e < 8; ++e) {
        const int flg = (f >> e) & 1;
        int lv = l[0];
#pragma unroll
        for (int qq = 1; qq < 8; ++qq) lv = (q == qq) ? l[qq] : lv;
        oh[e] = flg ? (_Float16)ov[e] : (_Float16)((float)lv * s);
        q += 1 - flg;
      }
    }
  } else {
    int c = 0;
    const int m = n8 - 1;
#pragma unroll
    for (int e = 0; e < 8; ++e) {
      const int flg = (f >> e) & 1;
      int idx = i0 + e - c;
      idx = idx < 0 ? 0 : (idx > m ? m : idx);
      oh[e] = flg ? (_Float16)ov[e] : (_Float16)((float)i8[idx] * s);
      c += flg;
    }
  }
  return oh;
}

// Per-chunk HBM prefetch bank — i8 + outlier values + meta-derived state
// ONLY (no A fragments: v8's 64-VGPR A banking hit the register wall and let
// the scheduler sink/de-pipeline the loads). Direct members (R6 SROA lesson).
struct Pre {
  int la[8], lb[8];          // i8 dwords for the lane's two B fragment slots
  int i0a, i0b;
  unsigned m8a, m8b;
  float va0, va1, vb0, vb1;  // prefetched outlier values (rank 0,1 per slot)
};

// ---------------------------------------------------------------------------
// Fused GEMM v9 — zero-barrier direct-to-MFMA pipeline, pressure-corrected.
// Iteration order (FIFO-safe): A(c) loads FIRST (transient regs, L2-resident
// x16) -> ISSUE i8/fpdat(c+1) + meta(c+2) -> FINISH b(c) (waits only loads
// older than A(c)) -> MFMA (waits A(c) at vmcnt(#i8(c+1)) — prefetch group
// stays in flight). Bank state ~24 VGPR x2 -> __launch_bounds__(256,4),
// 4 blocks/CU, 16 waves. No LDS / no barriers until the epilogue reduce.
// mfma_f32_16x16x32_f16 mapping + dequant numerics verified R1-R8.
// ---------------------------------------------------------------------------
__global__ __launch_bounds__(256, 4) void gemm_fused(
    const _Float16* __restrict__ x16, const int* __restrict__ i8,
    const float* __restrict__ fpdat, const float* __restrict__ scales,
    const int* __restrict__ meta, float* __restrict__ part,
    const int n8, const int nf) {
  __shared__ float red[4 * 64 * 16];  // 16 KB, epilogue only

  const int tid  = threadIdx.x;
  const int wave = tid >> 6;
  const int lane = tid & 63;
  const int quad = lane >> 4;
  const int ln   = lane & 15;
  const int nt   = blockIdx.x >> 2;
  const int kq   = blockIdx.x & 3;
  const int n0   = nt << 4;
  const int kbas = kq * 1024 + wave * 256;  // this wave's K base
  const int qoff = quad * 8;

  const int prow  = n0 + ln;
  const int pbase = prow * INF + kbas;      // positioned base of lane's row-K
  const float s   = scales[prow * 4 + kq];  // block-constant quant scale

#define ISSUE(BNK, CC, MV)                                                   \
  do {                                                                       \
    const int p0a_ = pbase + (CC) * 64 + qoff;                               \
    meta_window1(p0a_, (MV), BNK.i0a, BNK.m8a);                              \
    meta_window1(p0a_ + 32, (MV), BNK.i0b, BNK.m8b);                         \
    if (BNK.i0a + 8 <= n8) {                                                 \
      *(int4u*)&BNK.la[0] = *(const int4u*)&i8[BNK.i0a];                     \
      *(int4u*)&BNK.la[4] = *(const int4u*)&i8[BNK.i0a + 4];                 \
    }                                                                        \
    if (BNK.i0b + 8 <= n8) {                                                 \
      *(int4u*)&BNK.lb[0] = *(const int4u*)&i8[BNK.i0b];                     \
      *(int4u*)&BNK.lb[4] = *(const int4u*)&i8[BNK.i0b + 4];                 \
    }                                                                        \
    if (BNK.m8a) {                                                           \
      const int fia_ = p0a_ - BNK.i0a;                                       \
      BNK.va0 = fpdat[fia_];                                                 \
      BNK.va1 = fpdat[fia_ + 1 < nf ? fia_ + 1 : nf - 1];                    \
    }                                                                        \
    if (BNK.m8b) {                                                           \
      const int fib_ = p0a_ + 32 - BNK.i0b;                                  \
      BNK.vb0 = fpdat[fib_];                                                 \
      BNK.vb1 = fpdat[fib_ + 1 < nf ? fib_ + 1 : nf - 1];                    \
    }                                                                        \
  } while (0)

// Fast register-only combine (R8-verified): <=2 outliers per slot use
// prefetched V0/V1 by rank; int values via the q-walk select chain.
#define FSLOT(OH, LARR, M8, I0, V0, V1)                                      \
  do {                                                                       \
    const int f_ = (int)(M8);                                                \
    if ((I0) + 8 <= n8) {                                                    \
      if (f_ == 0) {                                                         \
        _Pragma("unroll")                                                    \
        for (int e = 0; e < 8; ++e) OH[e] = (_Float16)((float)LARR[e] * s);  \
      } else {                                                               \
        int q_ = 0;                                                          \
        _Pragma("unroll")                                                    \
        for (int e = 0; e < 8; ++e) {                                        \
          const int flg = (f_ >> e) & 1;                                     \
          const int rank = __popc(f_ & ((1 << e) - 1));                      \
          const float fv = (rank == 0) ? (V0) : (V1);                        \
          int lv = LARR[0];                                                  \
          _Pragma("unroll")                                                  \
          for (int qq = 1; qq < 8; ++qq) lv = (q_ == qq) ? LARR[qq] : lv;    \
          OH[e] = flg ? (_Float16)fv : (_Float16)((float)lv * s);            \
          q_ += 1 - flg;                                                     \
        }                                                                    \
      }                                                                      \
    } else {                                                                 \
      int c_ = 0;                                                            \
      const int m_ = n8 - 1;                                                 \
      _Pragma("unroll")                                                      \
      for (int e = 0; e < 8; ++e) {                                          \
        const int flg = (f_ >> e) & 1;                                       \
        const int rank = __popc(f_ & ((1 << e) - 1));                        \
        const float fv = (rank == 0) ? (V0) : (V1);                          \
        int idx = (I0) + e - c_;                                             \
        idx = idx < 0 ? 0 : (idx > m_ ? m_ : idx);                           \
        OH[e] = flg ? (_Float16)fv : (_Float16)((float)i8[idx] * s);         \
        c_ += flg;                                                           \
      }                                                                      \
    }                                                                        \
  } while (0)

// A-fragment loads for chunk CC into transient named regs A0..A7 (must be
// textually BEFORE the next chunk's ISSUE for FIFO-safe vmcnt counting).
#define LOADA(CC)                                                            \
  const _Float16* ap_ = &x16[ln * INF + kbas + (CC) * 64 + qoff];            \
  const half8 A0 = *(const half8*)&ap_[0];                                   \
  const half8 A1 = *(const half8*)&ap_[16 * INF];                            \
  const half8 A2 = *(const half8*)&ap_[32 * INF];                            \
  const half8 A3 = *(const half8*)&ap_[48 * INF];                            \
  const half8 A4 = *(const half8*)&ap_[32];                                  \
  const half8 A5 = *(const half8*)&ap_[16 * INF + 32];                       \
  const half8 A6 = *(const half8*)&ap_[32 * INF + 32];                       \
  const half8 A7 = *(const half8*)&ap_[48 * INF + 32]

#define FIN_MFMA(BNK, CC)                                                    \
  do {                                                                       \
    const int p0a_ = pbase + (CC) * 64 + qoff;                               \
    half8 b0, b1;                                                            \
    FSLOT(b0, BNK.la, BNK.m8a, BNK.i0a, BNK.va0, BNK.va1);                   \
    FSLOT(b1, BNK.lb, BNK.m8b, BNK.i0b, BNK.vb0, BNK.vb1);                   \
    if (__any(__popc((int)BNK.m8a) > 2 || __popc((int)BNK.m8b) > 2)) {       \
      if (__popc((int)BNK.m8a) > 2)                                          \
        b0 = finish_slot(BNK.m8a, BNK.i0a, p0a_, s, BNK.la, i8, fpdat, n8);  \
      if (__popc((int)BNK.m8b) > 2)                                          \
        b1 = finish_slot(BNK.m8b, BNK.i0b, p0a_ + 32, s, BNK.lb,             \
                         i8, fpdat, n8);                                     \
    }                                                                        \
    acc0 = __builtin_amdgcn_mfma_f32_16x16x32_f16(A0, b0, acc0, 0, 0, 0);    \
    acc1 = __builtin_amdgcn_mfma_f32_16x16x32_f16(A1, b0, acc1, 0, 0, 0);    \
    acc2 = __builtin_amdgcn_mfma_f32_16x16x32_f16(A2, b0, acc2, 0, 0, 0);    \
    acc3 = __builtin_amdgcn_mfma_f32_16x16x32_f16(A3, b0, acc3, 0, 0, 0);    \
    acc0 = __builtin_amdgcn_mfma_f32_16x16x32_f16(A4, b1, acc0, 0, 0, 0);    \
    acc1 = __builtin_amdgcn_mfma_f32_16x16x32_f16(A5, b1, acc1, 0, 0, 0);    \
    acc2 = __builtin_amdgcn_mfma_f32_16x16x32_f16(A6, b1, acc2, 0, 0, 0);    \
    acc3 = __builtin_amdgcn_mfma_f32_16x16x32_f16(A7, b1, acc3, 0, 0, 0);    \
  } while (0)

  // ---- Prologue: meta(0), meta(1); i8/fpdat(chunk 0) into bank A ----
  int4a mzA = *(const int4a*)&meta[(pbase >> 6) * 4];
  int4a mzB = *(const int4a*)&meta[((pbase + 64) >> 6) * 4];
  Pre pA, pB;
  ISSUE(pA, 0, mzA);

  floatx4 acc0 = {0,0,0,0}, acc1 = {0,0,0,0}, acc2 = {0,0,0,0}, acc3 = {0,0,0,0};

  // ---- Main loop, macro-unrolled; zero barriers, zero LDS ----
  {  // c = 0
    LOADA(0);
    ISSUE(pB, 1, mzB);
    mzA = *(const int4a*)&meta[((pbase + 128) >> 6) * 4];
    FIN_MFMA(pA, 0);
  }
  {  // c = 1
    LOADA(1);
    ISSUE(pA, 2, mzA);
    mzB = *(const int4a*)&meta[((pbase + 192) >> 6) * 4];
    FIN_MFMA(pB, 1);
  }
  {  // c = 2
    LOADA(2);
    ISSUE(pB, 3, mzB);
    FIN_MFMA(pA, 2);
  }
  {  // c = 3
    LOADA(3);
    FIN_MFMA(pB, 3);
  }

#undef ISSUE
#undef FSLOT
#undef LOADA
#undef FIN_MFMA

  // ---- Epilogue: cross-wave reduce (only barriers in the kernel) ----
  const int mb = quad * 4;
#pragma unroll
  for (int i = 0; i < 4; ++i) red[wave * 1024 + (mb + i)      * 16 + ln] = acc0[i];
#pragma unroll
  for (int i = 0; i < 4; ++i) red[wave * 1024 + (16 + mb + i) * 16 + ln] = acc1[i];
#pragma unroll
  for (int i = 0; i < 4; ++i) red[wave * 1024 + (32 + mb + i) * 16 + ln] = acc2[i];
#pragma unroll
  for (int i = 0; i < 4; ++i) red[wave * 1024 + (48 + mb + i) * 16 + ln] = acc3[i];
  __syncthreads();

  // ---- Plain partial store ----
  float* pp = &part[(size_t)kq * OUTN];
#pragma unroll
  for (int c2 = 0; c2 < 4; ++c2) {
    const int cell = tid + c2 * 256;  // 1024 cells = 64 m x 16 n
    const int mm = cell >> 4, nn = cell & 15;
    pp[mm * OUTF + n0 + nn] =
        red[cell] + red[1024 + cell] + red[2048 + cell] + red[3072 + cell];
  }
}

// ---------------------------------------------------------------------------
// Reduce: out = sum_kq part[kq] + bias. 11.3 MB read + 2.8 MB write ~ 3 us.
// ---------------------------------------------------------------------------
__global__ __launch_bounds__(256) void reduce_kernel(
    const float* __restrict__ part, const float* __restrict__ bias,
    float* __restrict__ out) {
  const int t  = blockIdx.x * 256 + threadIdx.x;  // 688*256 = 176128 exact
  const int i4 = t * 4;
  floatx4 a = *(const floatx4*)&part[i4];
#pragma unroll
  for (int k = 1; k < KSPL; ++k) {
    const floatx4 b = *(const floatx4*)&part[(size_t)k * OUTN + i4];
    a[0] += b[0]; a[1] += b[1]; a[2] += b[2]; a[3] += b[3];
  }
  const int nn = i4 % OUTF;  // OUTF % 4 == 0: float4 never straddles rows
  const floatx4 bb = *(const floatx4*)&bias[nn];
  a[0] += bb[0]; a[1] += bb[1]; a[2] += bb[2]; a[3] += bb[3];
  *(floatx4*)&out[i4] = a;
}

// ---------------------------------------------------------------------------
// Inputs: 0 x(fp32) 1 int8_data(i32) 2 fp16_data(fp32) 3 scales(fp32)
// 4 bias(fp32) 5 int8_pos(UNUSED) 6 fp16_pos(i32) 7 block_idx(UNUSED)
// ws: x16 (512 KB) | meta (11.3 MB) | part (11.3 MB) | seed (44 KB)
// ---------------------------------------------------------------------------
extern "C" void kernel_launch(void* const* d_in, const int* in_sizes, int n_in,
                              void* d_out, int out_size, void* d_ws,
                              size_t ws_size, hipStream_t stream) {
  const float* x      = (const float*)d_in[0];
  const int*   i8     = (const int*)d_in[1];
  const float* fpdat  = (const float*)d_in[2];
  const float* scales = (const float*)d_in[3];
  const float* bias   = (const float*)d_in[4];
  const int*   fppos  = (const int*)d_in[6];

  char* wsp = (char*)d_ws;
  _Float16* x16  = (_Float16*)wsp;
  int*      meta = (int*)(wsp + (size_t)TOK * INF * sizeof(_Float16));
  float*    part = (float*)(wsp + (size_t)TOK * INF * sizeof(_Float16)
                                + (size_t)NSLC * 16);
  int*      seed = (int*)(wsp + (size_t)TOK * INF * sizeof(_Float16)
                              + (size_t)NSLC * 16
                              + (size_t)KSPL * OUTN * sizeof(float));
  float*    out  = (float*)d_out;

  const int n8 = in_sizes[1];
  const int nf = in_sizes[2];

  seed_kernel<<<(NSEED + 256) / 256 + 1, 256, 0, stream>>>(fppos, nf, seed);
  precompute_kernel<<<NSLC / 256, 256, 0, stream>>>(x, fppos, nf, seed,
                                                    x16, meta);
  gemm_fused<<<NBLK * KSPL, 256, 0, stream>>>(x16, i8, fpdat, scales, meta,
                                              part, n8, nf);
  reduce_kernel<<<OUTN / (4 * 256), 256, 0, stream>>>(part, bias, out);
}